// Round 7
// baseline (23.871 us; speedup 1.0000x reference)
//
#include <hip/hip_runtime.h>

#define NBINS 256
#define ROWS 96                    // b*c = 32*3
#define ROW_N (512 * 512)          // 262144 elements per row
#define BPR 8                      // blocks per row
#define CHUNK (ROW_N / BPR)        // 32768 elements per block
#define BLOCK 512
#define WAVES (BLOCK / 64)         // 8
#define BIN_W 0.99609375f          // (255-0)/256, exactly representable
#define RECIP_W 1.00392156862745098f  // fl(256/255)
#define WS_NEEDED ((size_t)ROWS * BPR * NBINS * sizeof(unsigned int))

// exact floor(fv / BIN_W) without v_div: multiply-estimate + exact fixup.
// bf*BIN_W and (bf+1)*BIN_W are EXACT in fp32 (b <= 256 -> b*255 < 2^17),
// so the compares compute the true floor. Verified bit-exact (R3-R6 absmax=0).
__device__ __forceinline__ void bin_hit(float fv, unsigned int* lhw) {
    float bf = truncf(fv * RECIP_W);
    float t = bf * BIN_W;
    int b = (int)bf + (int)((t + BIN_W) <= fv) - (int)(t > fv);
    b = b > NBINS - 1 ? NBINS - 1 : b;        // also maps fv==255 -> 255
    bool valid = (fv >= 0.0f) && (fv <= 255.0f);   // NaN -> false
    atomicAdd(&lhw[valid ? b : NBINS], 1u);   // invalid -> trash slot
}

#define PROC4(v) do { bin_hit((v).x, lhw); bin_hit((v).y, lhw); \
                      bin_hit((v).z, lhw); bin_hit((v).w, lhw); } while (0)

template <bool USE_WS>
__global__ __launch_bounds__(BLOCK) void nh_hist(const float* __restrict__ x,
                                                 unsigned int* __restrict__ ws,
                                                 float* __restrict__ out) {
    __shared__ unsigned int lh[WAVES][NBINS + 1];   // +1 = trash for invalid
    const int tid = threadIdx.x;
    unsigned int* lhw = lh[tid >> 6];

    #pragma unroll
    for (int i = tid; i < WAVES * (NBINS + 1); i += BLOCK)
        ((unsigned int*)lh)[i] = 0u;
    __syncthreads();

    const int row = blockIdx.y;
    const float4* __restrict__ p =
        (const float4*)(x + (size_t)row * ROW_N + (size_t)blockIdx.x * CHUNK);

    // 16 float4/thread in 4 groups of 4; software pipeline: issue group g+1's
    // loads BEFORE processing group g, so 4 KB/wave stays in flight across
    // the DS-atomic phase (R5 showed VGPR=16 -> compiler kept only 1 load
    // outstanding; 24 KB/CU in flight was at the BW-delay product edge).
    float4 c0 = p[tid];
    float4 c1 = p[tid + BLOCK];
    float4 c2 = p[tid + 2 * BLOCK];
    float4 c3 = p[tid + 3 * BLOCK];
    #pragma unroll
    for (int g = 1; g < 4; ++g) {
        const int off = g * 4 * BLOCK + tid;
        float4 n0 = p[off];
        float4 n1 = p[off + BLOCK];
        float4 n2 = p[off + 2 * BLOCK];
        float4 n3 = p[off + 3 * BLOCK];
        PROC4(c0); PROC4(c1); PROC4(c2); PROC4(c3);
        c0 = n0; c1 = n1; c2 = n2; c3 = n3;
    }
    PROC4(c0); PROC4(c1); PROC4(c2); PROC4(c3);
    __syncthreads();

    // cross-wave reduce (lh[w][tid] stride 257 words -> conflict-free)
    if (tid < NBINS) {
        unsigned int total = 0;
        #pragma unroll
        for (int w = 0; w < WAVES; ++w) total += lh[w][tid];

        if (USE_WS) {
            // non-atomic coalesced partial; block owns its slot
            ws[((size_t)row * BPR + blockIdx.x) * NBINS + tid] = total;
        } else {
            // fallback: float atomic into pre-zeroed out (exact: multiples
            // of 2^-18, k <= 2^18 < 2^24 -> order-independent)
            atomicAdd(&out[row * NBINS + tid], (float)total * (1.0f / ROW_N));
        }
    }
}

__global__ void nh_reduce(const unsigned int* __restrict__ ws,
                          float* __restrict__ out) {
    const int row = blockIdx.x;
    const int bin = threadIdx.x;
    unsigned int s = 0;
    #pragma unroll
    for (int j = 0; j < BPR; ++j)
        s += ws[((size_t)row * BPR + j) * NBINS + bin];
    out[row * NBINS + bin] = (float)s * (1.0f / ROW_N);  // exact
}

__global__ void nh_zero_out(float* __restrict__ out) {
    out[blockIdx.x * NBINS + threadIdx.x] = 0.0f;
}

extern "C" void kernel_launch(void* const* d_in, const int* in_sizes, int n_in,
                              void* d_out, int out_size, void* d_ws, size_t ws_size,
                              hipStream_t stream) {
    const float* x = (const float*)d_in[0];
    float* out = (float*)d_out;
    unsigned int* ws = (unsigned int*)d_ws;

    dim3 grid(BPR, ROWS);
    if (ws_size >= WS_NEEDED) {
        nh_hist<true><<<grid, BLOCK, 0, stream>>>(x, ws, out);
        nh_reduce<<<ROWS, NBINS, 0, stream>>>(ws, out);
    } else {
        nh_zero_out<<<ROWS, NBINS, 0, stream>>>(out);
        nh_hist<false><<<grid, BLOCK, 0, stream>>>(x, ws, out);
    }
}

// Round 8
// 22.924 us; speedup vs baseline: 1.0413x; 1.0413x over previous
//
#include <hip/hip_runtime.h>

#define NBINS 256
#define ROWS 96                    // b*c = 32*3
#define ROW_N (512 * 512)          // 262144 elements per row
#define BPR 8                      // blocks per row
#define CHUNK (ROW_N / BPR)        // 32768 elements per block
#define BLOCK 1024
#define WAVES (BLOCK / 64)         // 16
#define BIN_W 0.99609375f          // (255-0)/256, exactly representable
#define RECIP_W 1.00392156862745098f  // fl(256/255)
#define WS_NEEDED ((size_t)ROWS * BPR * NBINS * sizeof(unsigned int))

// exact floor(fv / BIN_W) without v_div: multiply-estimate + exact fixup.
// bf*BIN_W and (bf+1)*BIN_W are EXACT in fp32 (b <= 256 -> b*255 < 2^17),
// so the compares compute the true floor. Verified bit-exact (R3-R7 absmax=0).
__device__ __forceinline__ void bin_hit(float fv, unsigned int* lhw) {
    float bf = truncf(fv * RECIP_W);
    float t = bf * BIN_W;
    int b = (int)bf + (int)((t + BIN_W) <= fv) - (int)(t > fv);
    b = b > NBINS - 1 ? NBINS - 1 : b;        // also maps fv==255 -> 255
    bool valid = (fv >= 0.0f) && (fv <= 255.0f);   // NaN -> false
    atomicAdd(&lhw[valid ? b : NBINS], 1u);   // invalid -> trash slot
}

template <bool USE_WS>
__global__ __launch_bounds__(BLOCK) void nh_hist(const float* __restrict__ x,
                                                 unsigned int* __restrict__ ws,
                                                 float* __restrict__ out) {
    __shared__ unsigned int lh[WAVES][NBINS + 1];   // +1 = trash for invalid
    const int tid = threadIdx.x;
    unsigned int* lhw = lh[tid >> 6];

    for (int i = tid; i < WAVES * (NBINS + 1); i += BLOCK)
        ((unsigned int*)lh)[i] = 0u;
    __syncthreads();

    const int row = blockIdx.y;
    const float4* __restrict__ p =
        (const float4*)(x + (size_t)row * ROW_N + (size_t)blockIdx.x * CHUNK);

    // 8 float4 per thread; modest unroll (R7 showed aggressive hoisting hurts)
    #pragma unroll 4
    for (int i = tid; i < CHUNK / 4; i += BLOCK) {
        float4 v = p[i];
        bin_hit(v.x, lhw); bin_hit(v.y, lhw);
        bin_hit(v.z, lhw); bin_hit(v.w, lhw);
    }
    __syncthreads();

    // cross-wave reduce (stride 257 words -> 2 lanes/bank, conflict-free)
    if (tid < NBINS) {
        unsigned int total = 0;
        #pragma unroll
        for (int w = 0; w < WAVES; ++w) total += lh[w][tid];

        if (USE_WS) {
            // non-atomic coalesced partial; block owns its slot
            ws[((size_t)row * BPR + blockIdx.x) * NBINS + tid] = total;
        } else {
            // fallback: float atomic into pre-zeroed out (exact: multiples
            // of 2^-18, k <= 2^18 < 2^24 -> order-independent)
            atomicAdd(&out[row * NBINS + tid], (float)total * (1.0f / ROW_N));
        }
    }
}

// latency-bound: spread over 192 blocks (2 per row) for more CU parallelism
__global__ void nh_reduce(const unsigned int* __restrict__ ws,
                          float* __restrict__ out) {
    const int row = blockIdx.x >> 1;
    const int bin = ((blockIdx.x & 1) << 7) + threadIdx.x;   // 128 bins/block
    unsigned int s = 0;
    #pragma unroll
    for (int j = 0; j < BPR; ++j)
        s += ws[((size_t)row * BPR + j) * NBINS + bin];
    out[row * NBINS + bin] = (float)s * (1.0f / ROW_N);  // exact
}

__global__ void nh_zero_out(float* __restrict__ out) {
    out[blockIdx.x * NBINS + threadIdx.x] = 0.0f;
}

extern "C" void kernel_launch(void* const* d_in, const int* in_sizes, int n_in,
                              void* d_out, int out_size, void* d_ws, size_t ws_size,
                              hipStream_t stream) {
    const float* x = (const float*)d_in[0];
    float* out = (float*)d_out;
    unsigned int* ws = (unsigned int*)d_ws;

    dim3 grid(BPR, ROWS);
    if (ws_size >= WS_NEEDED) {
        nh_hist<true><<<grid, BLOCK, 0, stream>>>(x, ws, out);
        nh_reduce<<<ROWS * 2, 128, 0, stream>>>(ws, out);
    } else {
        nh_zero_out<<<ROWS, NBINS, 0, stream>>>(out);
        nh_hist<false><<<grid, BLOCK, 0, stream>>>(x, ws, out);
    }
}